// Round 3
// baseline (667.280 us; speedup 1.0000x reference)
//
#include <hip/hip_runtime.h>
#include <math.h>

#define NW 100000
#define NS 10000
#define NE 800000
#define DIM 256
#define NH 4
#define DFF 512
#define NEG_SLOPE 0.2f
#define CAP 64   // bucket capacity per word node; deg ~ Poisson(8), P(>64) ~ 0

typedef __attribute__((ext_vector_type(8))) short bf16x8;
typedef __attribute__((ext_vector_type(4))) float floatx4;

// ---------------- helpers ----------------
__device__ __forceinline__ float wave_max64(float v) {
#pragma unroll
    for (int m = 32; m; m >>= 1) v = fmaxf(v, __shfl_xor(v, m, 64));
    return v;
}
__device__ __forceinline__ float wave_sum64(float v) {
#pragma unroll
    for (int m = 32; m; m >>= 1) v += __shfl_xor(v, m, 64);
    return v;
}
__device__ __forceinline__ unsigned short f2bf(float f) {  // RNE fp32->bf16
    unsigned int u = __float_as_uint(f);
    unsigned int r = (u + 0x7fffu + ((u >> 16) & 1u)) >> 16;
    return (unsigned short)r;
}
__device__ __forceinline__ float bf2f(unsigned short u) {
    return __uint_as_float(((unsigned int)u) << 16);
}

// ---------------- small kernels ----------------

__global__ void zero_count(int* __restrict__ count) {
    int i = blockIdx.x * 256 + threadIdx.x;
    if (i < NW) count[i] = 0;
}

// C[k,h] = sum_d W[k, h*64+d] * A[h,d]
__global__ void compute_C(const float* __restrict__ W_src, const float* __restrict__ attn_l,
                          const float* __restrict__ W_dst, const float* __restrict__ attn_r,
                          float* __restrict__ C_src, float* __restrict__ C_dst) {
    const float* W = blockIdx.x ? W_dst : W_src;
    const float* A = blockIdx.x ? attn_r : attn_l;
    float* C = blockIdx.x ? C_dst : C_src;
    int k = threadIdx.x;
#pragma unroll
    for (int h = 0; h < NH; h++) {
        const float4* Wv = (const float4*)(W + (size_t)k * DIM + h * 64);
        const float4* Av = (const float4*)(A + h * 64);
        float s = 0.f;
#pragma unroll
        for (int d = 0; d < 16; d++) {
            float4 w = Wv[d], a = Av[d];
            s += w.x * a.x + w.y * a.y + w.z * a.z + w.w * a.w;
        }
        C[k * NH + h] = s;
    }
}

// out[n,h] = X[n,:] @ C[:,h]; one wave per row (el only, NS rows)
__global__ __launch_bounds__(256) void rowdot(const float* __restrict__ X,
                                              const float* __restrict__ C,
                                              float* __restrict__ out, int N) {
    int wave = (blockIdx.x * blockDim.x + threadIdx.x) >> 6;
    int lane = threadIdx.x & 63;
    if (wave >= N) return;
    float4 x = ((const float4*)(X + (size_t)wave * DIM))[lane];
    const float4* Cv = (const float4*)C;
    float4 c0 = Cv[lane * 4 + 0], c1 = Cv[lane * 4 + 1], c2 = Cv[lane * 4 + 2], c3 = Cv[lane * 4 + 3];
    float p0 = x.x * c0.x + x.y * c1.x + x.z * c2.x + x.w * c3.x;
    float p1 = x.x * c0.y + x.y * c1.y + x.z * c2.y + x.w * c3.y;
    float p2 = x.x * c0.z + x.y * c1.z + x.z * c2.z + x.w * c3.z;
    float p3 = x.x * c0.w + x.y * c1.w + x.z * c2.w + x.w * c3.w;
    p0 = wave_sum64(p0); p1 = wave_sum64(p1); p2 = wave_sum64(p2); p3 = wave_sum64(p3);
    if (lane == 0) {
        out[(size_t)wave * NH + 0] = p0; out[(size_t)wave * NH + 1] = p1;
        out[(size_t)wave * NH + 2] = p2; out[(size_t)wave * NH + 3] = p3;
    }
}

// feat16 = bf16(sent @ W_src) : [NS,256]
__global__ __launch_bounds__(256) void feat_gemm(const float* __restrict__ X,
                                                 const float* __restrict__ W,
                                                 unsigned short* __restrict__ out) {
    __shared__ float a[16][DIM];
    int t = threadIdx.x;
    int rg = t >> 6;
    int lane = t & 63;
    int c0 = lane * 4;
    size_t row0 = (size_t)blockIdx.x * 16;
#pragma unroll 4
    for (int i = 0; i < 16; i++) a[i][t] = X[(row0 + i) * DIM + t];
    __syncthreads();
    float acc[4][4] = {};
    for (int kk = 0; kk < DIM; kk += 4) {
        float af[4][4];
#pragma unroll
        for (int i = 0; i < 4; i++) {
            float4 v = *(const float4*)&a[rg * 4 + i][kk];
            af[i][0] = v.x; af[i][1] = v.y; af[i][2] = v.z; af[i][3] = v.w;
        }
        float wf[4][4];
#pragma unroll
        for (int j2 = 0; j2 < 4; j2++) {
            float4 v = *(const float4*)&W[(size_t)(kk + j2) * DIM + c0];
            wf[j2][0] = v.x; wf[j2][1] = v.y; wf[j2][2] = v.z; wf[j2][3] = v.w;
        }
#pragma unroll
        for (int i = 0; i < 4; i++)
#pragma unroll
            for (int j2 = 0; j2 < 4; j2++)
#pragma unroll
                for (int j = 0; j < 4; j++)
                    acc[i][j] = fmaf(af[i][j2], wf[j2][j], acc[i][j]);
    }
#pragma unroll
    for (int i = 0; i < 4; i++) {
        ushort4 p;
        p.x = f2bf(acc[i][0]); p.y = f2bf(acc[i][1]);
        p.z = f2bf(acc[i][2]); p.w = f2bf(acc[i][3]);
        *(ushort4*)&out[(row0 + rg * 4 + i) * DIM + c0] = p;
    }
}

__global__ void scatter_edges(const int* __restrict__ src, const int* __restrict__ dst,
                              int* __restrict__ count, unsigned short* __restrict__ bucket) {
    int e = blockIdx.x * 256 + threadIdx.x;
    if (e >= NE) return;
    int w = dst[e];
    int pos = atomicAdd(&count[w], 1);
    if (pos < CAP) bucket[(size_t)w * CAP + pos] = (unsigned short)src[e];
}

// transpose + convert weights: w1t[n][k]=bf16(w1[k][n]) (512x256), w2t[n][k]=bf16(w2[k][n]) (256x512)
__global__ void prep_weights(const float* __restrict__ w1, const float* __restrict__ w2,
                             unsigned short* __restrict__ w1t, unsigned short* __restrict__ w2t) {
    int b = blockIdx.x, t = threadIdx.x;
    if (b < DFF) {
        w1t[(size_t)b * 256 + t] = f2bf(w1[(size_t)t * DFF + b]);
    } else {
        int n = b - DFF;
        w2t[(size_t)n * DFF + t]       = f2bf(w2[(size_t)t * 256 + n]);
        w2t[(size_t)n * DFF + t + 256] = f2bf(w2[(size_t)(t + 256) * 256 + n]);
    }
}

// ---------------- fused GAT + FFN ----------------
// Block = 32 word nodes (4 waves x 8 nodes). GAT aggregate -> h bf16 in LDS ->
// GEMM1 (w1t direct-from-global B-frags) -> hid bf16 in LDS -> GEMM2 -> fp32 out.
// LDS XOR swizzle: 16B granule g of row r stored at slot (g&~7)|((g^r)&7):
// rows r and r+8 alias -> 2-way conflicts only (free on CDNA4).
__global__ __launch_bounds__(256, 3) void fused_gat_ffn(
    const int* __restrict__ count, const unsigned short* __restrict__ bucket,
    const float* __restrict__ el, const float* __restrict__ Cdst,
    const unsigned short* __restrict__ feat16, const float* __restrict__ word,
    const float* __restrict__ gat_bias,
    const unsigned short* __restrict__ w1t, const float* __restrict__ b1,
    const unsigned short* __restrict__ w2t, const float* __restrict__ b2,
    float* __restrict__ out)
{
    __shared__ unsigned short Als[32 * 256];   // 16 KB : h tile, bf16
    __shared__ unsigned short Hls[32 * 512];   // 32 KB : hid tile, bf16
    const int tid = threadIdx.x;
    const int lane = tid & 63, wv = tid >> 6;
    const int l15 = lane & 15, quad = lane >> 4;
    const int row0 = blockIdx.x * 32;

    // ---- GAT phase: wave wv handles nodes row0 + wv*8 + j ----
    {
        const float4* Cv = (const float4*)Cdst;
        float4 cd0 = Cv[lane * 4 + 0], cd1 = Cv[lane * 4 + 1];
        float4 cd2 = Cv[lane * 4 + 2], cd3 = Cv[lane * 4 + 3];
        float4 gb = ((const float4*)gat_bias)[lane];
        int hh = lane >> 4;  // head owning this lane's 4 cols
        for (int j = 0; j < 8; j++) {
            int r = wv * 8 + j;
            int node = row0 + r;
            int deg = count[node]; if (deg > CAP) deg = CAP;
            float4 wrow = ((const float4*)(word + (size_t)node * DIM))[lane];
            // er inline (replaces rowdot over NW)
            float p0 = wrow.x * cd0.x + wrow.y * cd1.x + wrow.z * cd2.x + wrow.w * cd3.x;
            float p1 = wrow.x * cd0.y + wrow.y * cd1.y + wrow.z * cd2.y + wrow.w * cd3.y;
            float p2 = wrow.x * cd0.z + wrow.y * cd1.z + wrow.z * cd2.z + wrow.w * cd3.z;
            float p3 = wrow.x * cd0.w + wrow.y * cd1.w + wrow.z * cd2.w + wrow.w * cd3.w;
            p0 = wave_sum64(p0); p1 = wave_sum64(p1);
            p2 = wave_sum64(p2); p3 = wave_sum64(p3);
            int s = 0;
            float e0 = -3.4e38f, e1 = -3.4e38f, e2 = -3.4e38f, e3 = -3.4e38f;
            if (lane < deg) {
                s = bucket[(size_t)node * CAP + lane];
                float4 elv = ((const float4*)el)[s];
                float v;
                v = elv.x + p0; e0 = v > 0.f ? v : NEG_SLOPE * v;
                v = elv.y + p1; e1 = v > 0.f ? v : NEG_SLOPE * v;
                v = elv.z + p2; e2 = v > 0.f ? v : NEG_SLOPE * v;
                v = elv.w + p3; e3 = v > 0.f ? v : NEG_SLOPE * v;
            }
            float m0 = wave_max64(e0), m1 = wave_max64(e1), m2 = wave_max64(e2), m3 = wave_max64(e3);
            float x0 = lane < deg ? expf(e0 - m0) : 0.f;
            float x1 = lane < deg ? expf(e1 - m1) : 0.f;
            float x2 = lane < deg ? expf(e2 - m2) : 0.f;
            float x3 = lane < deg ? expf(e3 - m3) : 0.f;
            float d0 = wave_sum64(x0), d1 = wave_sum64(x1), d2 = wave_sum64(x2), d3 = wave_sum64(x3);
            float a0 = x0 / d0, a1 = x1 / d1, a2 = x2 / d2, a3 = x3 / d3;

            float4 acc = {0.f, 0.f, 0.f, 0.f};
            for (int i = 0; i < deg; i++) {
                int si = __shfl(s, i, 64);
                float q0 = __shfl(a0, i, 64), q1 = __shfl(a1, i, 64);
                float q2 = __shfl(a2, i, 64), q3 = __shfl(a3, i, 64);
                float aa = hh == 0 ? q0 : hh == 1 ? q1 : hh == 2 ? q2 : q3;
                ushort4 f = ((const ushort4*)(feat16 + (size_t)si * DIM))[lane];
                acc.x = fmaf(aa, bf2f(f.x), acc.x);
                acc.y = fmaf(aa, bf2f(f.y), acc.y);
                acc.z = fmaf(aa, bf2f(f.z), acc.z);
                acc.w = fmaf(aa, bf2f(f.w), acc.w);
            }
            float4 rr;
            rr.x = acc.x + gb.x; rr.x = rr.x > 0.f ? rr.x : (expf(rr.x) - 1.f);
            rr.y = acc.y + gb.y; rr.y = rr.y > 0.f ? rr.y : (expf(rr.y) - 1.f);
            rr.z = acc.z + gb.z; rr.z = rr.z > 0.f ? rr.z : (expf(rr.z) - 1.f);
            rr.w = acc.w + gb.w; rr.w = rr.w > 0.f ? rr.w : (expf(rr.w) - 1.f);
            ushort4 hp;
            hp.x = f2bf(wrow.x + rr.x); hp.y = f2bf(wrow.y + rr.y);
            hp.z = f2bf(wrow.z + rr.z); hp.w = f2bf(wrow.w + rr.w);
            int g = lane >> 1;  // 16B granule = 8 cols; lane writes cols 4l..4l+3
            int slot = (g & ~7) | ((g ^ r) & 7);
            *(ushort4*)&Als[r * 256 + slot * 8 + (lane & 1) * 4] = hp;
        }
    }
    __syncthreads();

    // ---- Phase 1: hid = relu(h @ w1 + b1), wave wv owns cols [wv*128, +128) ----
    for (int ch = 0; ch < 2; ch++) {
        int c0 = wv * 128 + ch * 64;
        floatx4 acc[2][4];
#pragma unroll
        for (int mt = 0; mt < 2; mt++)
#pragma unroll
            for (int nt = 0; nt < 4; nt++) acc[mt][nt] = (floatx4){0.f, 0.f, 0.f, 0.f};
#pragma unroll
        for (int ks = 0; ks < 8; ks++) {
            bf16x8 a[2], b[4];
#pragma unroll
            for (int mt = 0; mt < 2; mt++) {
                int r = mt * 16 + l15;
                int g = ks * 4 + quad;
                int slot = (g & ~7) | ((g ^ r) & 7);
                a[mt] = *(const bf16x8*)&Als[r * 256 + slot * 8];
            }
#pragma unroll
            for (int nt = 0; nt < 4; nt++)
                b[nt] = *(const bf16x8*)&w1t[(size_t)(c0 + nt * 16 + l15) * 256 + ks * 32 + quad * 8];
#pragma unroll
            for (int mt = 0; mt < 2; mt++)
#pragma unroll
                for (int nt = 0; nt < 4; nt++)
                    acc[mt][nt] = __builtin_amdgcn_mfma_f32_16x16x32_bf16(a[mt], b[nt], acc[mt][nt], 0, 0, 0);
        }
#pragma unroll
        for (int nt = 0; nt < 4; nt++) {
            int c = c0 + nt * 16 + l15;
            float bias = b1[c];
            int g = c >> 3;
#pragma unroll
            for (int mt = 0; mt < 2; mt++)
#pragma unroll
                for (int i = 0; i < 4; i++) {
                    int r = mt * 16 + quad * 4 + i;
                    float v = acc[mt][nt][i] + bias;
                    v = v > 0.f ? v : 0.f;
                    int slot = (g & ~7) | ((g ^ r) & 7);
                    Hls[r * 512 + slot * 8 + (c & 7)] = f2bf(v);
                }
        }
    }
    __syncthreads();

    // ---- Phase 2: out = hid @ w2 + b2, wave wv owns cols [wv*64, +64) ----
    floatx4 acc2[2][4];
#pragma unroll
    for (int mt = 0; mt < 2; mt++)
#pragma unroll
        for (int nt = 0; nt < 4; nt++) acc2[mt][nt] = (floatx4){0.f, 0.f, 0.f, 0.f};
#pragma unroll
    for (int ks = 0; ks < 16; ks++) {
        bf16x8 a[2], b[4];
#pragma unroll
        for (int mt = 0; mt < 2; mt++) {
            int r = mt * 16 + l15;
            int g = ks * 4 + quad;
            int slot = (g & ~7) | ((g ^ r) & 7);
            a[mt] = *(const bf16x8*)&Hls[r * 512 + slot * 8];
        }
#pragma unroll
        for (int nt = 0; nt < 4; nt++) {
            int n = wv * 64 + nt * 16 + l15;
            b[nt] = *(const bf16x8*)&w2t[(size_t)n * 512 + ks * 32 + quad * 8];
        }
#pragma unroll
        for (int mt = 0; mt < 2; mt++)
#pragma unroll
            for (int nt = 0; nt < 4; nt++)
                acc2[mt][nt] = __builtin_amdgcn_mfma_f32_16x16x32_bf16(a[mt], b[nt], acc2[mt][nt], 0, 0, 0);
    }
#pragma unroll
    for (int nt = 0; nt < 4; nt++) {
        int c = wv * 64 + nt * 16 + l15;
        float bias = b2[c];
#pragma unroll
        for (int mt = 0; mt < 2; mt++)
#pragma unroll
            for (int i = 0; i < 4; i++)
                out[(size_t)(row0 + mt * 16 + quad * 4 + i) * DIM + c] = acc2[mt][nt][i] + bias;
    }
}

// ---------------- launch ----------------
extern "C" void kernel_launch(void* const* d_in, const int* in_sizes, int n_in,
                              void* d_out, int out_size, void* d_ws, size_t ws_size,
                              hipStream_t stream) {
    const float* word   = (const float*)d_in[0];
    const float* sent   = (const float*)d_in[1];
    const int*   src    = (const int*)d_in[2];
    const int*   dst    = (const int*)d_in[3];
    const float* W_src  = (const float*)d_in[4];
    const float* W_dst  = (const float*)d_in[5];
    const float* attn_l = (const float*)d_in[6];
    const float* attn_r = (const float*)d_in[7];
    const float* gbias  = (const float*)d_in[8];
    const float* w1     = (const float*)d_in[9];
    const float* b1     = (const float*)d_in[10];
    const float* w2     = (const float*)d_in[11];
    const float* b2     = (const float*)d_in[12];
    float* out = (float*)d_out;

    char* wsb = (char*)d_ws;
    unsigned short* w1t = (unsigned short*)wsb;                 // 512*256
    unsigned short* w2t = w1t + (size_t)DFF * 256;              // 256*512
    float* el    = (float*)(w2t + (size_t)256 * DFF);           // NS*4
    float* C_src = el + (size_t)NS * NH;                        // 1024
    float* C_dst = C_src + DIM * NH;                            // 1024
    unsigned short* feat16 = (unsigned short*)(C_dst + DIM * NH);  // NS*256
    int* count = (int*)(feat16 + (size_t)NS * DIM);             // NW
    unsigned short* bucket = (unsigned short*)(count + NW);     // NW*CAP
    // total ~19 MB

    hipLaunchKernelGGL(zero_count, dim3((NW + 255) / 256), dim3(256), 0, stream, count);
    hipLaunchKernelGGL(compute_C, dim3(2), dim3(256), 0, stream,
                       W_src, attn_l, W_dst, attn_r, C_src, C_dst);
    hipLaunchKernelGGL(prep_weights, dim3(DFF + 256), dim3(256), 0, stream, w1, w2, w1t, w2t);
    hipLaunchKernelGGL(rowdot, dim3(NS / 4), dim3(256), 0, stream, sent, C_src, el, NS);
    hipLaunchKernelGGL(feat_gemm, dim3(NS / 16), dim3(256), 0, stream, sent, W_src, feat16);
    hipLaunchKernelGGL(scatter_edges, dim3(NE / 256), dim3(256), 0, stream, src, dst, count, bucket);
    hipLaunchKernelGGL(fused_gat_ffn, dim3(NW / 32), dim3(256), 0, stream,
                       count, bucket, el, C_dst, feat16, word, gbias,
                       w1t, b1, w2t, b2, out);
}

// Round 4
// 558.397 us; speedup vs baseline: 1.1950x; 1.1950x over previous
//
#include <hip/hip_runtime.h>
#include <math.h>

#define NW 100000
#define NS 10000
#define NE 800000
#define DIM 256
#define NH 4
#define DFF 512
#define NEG_SLOPE 0.2f
#define CAP 64   // bucket capacity; deg ~ Poisson(8), P(>64) ~ 0

typedef __attribute__((ext_vector_type(8))) short bf16x8;
typedef __attribute__((ext_vector_type(8))) unsigned short ushortx8;
typedef __attribute__((ext_vector_type(16))) float floatx16;

// ---------------- helpers ----------------
__device__ __forceinline__ unsigned short f2bf(float f) {  // RNE fp32->bf16
    unsigned int u = __float_as_uint(f);
    unsigned int r = (u + 0x7fffu + ((u >> 16) & 1u)) >> 16;
    return (unsigned short)r;
}
__device__ __forceinline__ float bf2f(unsigned short u) {
    return __uint_as_float(((unsigned int)u) << 16);
}
__device__ __forceinline__ void gload_lds16(const void* g, void* l) {
    __builtin_amdgcn_global_load_lds(
        (const __attribute__((address_space(1))) unsigned int*)g,
        (__attribute__((address_space(3))) unsigned int*)l, 16, 0, 0);
}
__device__ __forceinline__ float wave_sum64(float v) {
#pragma unroll
    for (int m = 32; m; m >>= 1) v += __shfl_xor(v, m, 64);
    return v;
}

// ---------------- small kernels ----------------

__global__ void zero_count(int* __restrict__ count) {
    int i = blockIdx.x * 256 + threadIdx.x;
    if (i < NW) count[i] = 0;
}

// C[k,h] = sum_d W[k, h*64+d] * A[h,d]
__global__ void compute_C(const float* __restrict__ W_src, const float* __restrict__ attn_l,
                          const float* __restrict__ W_dst, const float* __restrict__ attn_r,
                          float* __restrict__ C_src, float* __restrict__ C_dst) {
    const float* W = blockIdx.x ? W_dst : W_src;
    const float* A = blockIdx.x ? attn_r : attn_l;
    float* C = blockIdx.x ? C_dst : C_src;
    int k = threadIdx.x;
#pragma unroll
    for (int h = 0; h < NH; h++) {
        const float4* Wv = (const float4*)(W + (size_t)k * DIM + h * 64);
        const float4* Av = (const float4*)(A + h * 64);
        float s = 0.f;
#pragma unroll
        for (int d = 0; d < 16; d++) {
            float4 w = Wv[d], a = Av[d];
            s += w.x * a.x + w.y * a.y + w.z * a.z + w.w * a.w;
        }
        C[k * NH + h] = s;
    }
}

// el[n,h] = sent[n,:] @ C_src[:,h]; one wave per row
__global__ __launch_bounds__(256) void rowdot(const float* __restrict__ X,
                                              const float* __restrict__ C,
                                              float* __restrict__ out, int N) {
    int wave = (blockIdx.x * blockDim.x + threadIdx.x) >> 6;
    int lane = threadIdx.x & 63;
    if (wave >= N) return;
    float4 x = ((const float4*)(X + (size_t)wave * DIM))[lane];
    const float4* Cv = (const float4*)C;
    float4 c0 = Cv[lane * 4 + 0], c1 = Cv[lane * 4 + 1], c2 = Cv[lane * 4 + 2], c3 = Cv[lane * 4 + 3];
    float p0 = x.x * c0.x + x.y * c1.x + x.z * c2.x + x.w * c3.x;
    float p1 = x.x * c0.y + x.y * c1.y + x.z * c2.y + x.w * c3.y;
    float p2 = x.x * c0.z + x.y * c1.z + x.z * c2.z + x.w * c3.z;
    float p3 = x.x * c0.w + x.y * c1.w + x.z * c2.w + x.w * c3.w;
    p0 = wave_sum64(p0); p1 = wave_sum64(p1); p2 = wave_sum64(p2); p3 = wave_sum64(p3);
    if (lane == 0) {
        out[(size_t)wave * NH + 0] = p0; out[(size_t)wave * NH + 1] = p1;
        out[(size_t)wave * NH + 2] = p2; out[(size_t)wave * NH + 3] = p3;
    }
}

// feat16 = bf16(sent @ W_src) : [NS,256]
__global__ __launch_bounds__(256) void feat_gemm(const float* __restrict__ X,
                                                 const float* __restrict__ W,
                                                 unsigned short* __restrict__ out) {
    __shared__ float a[16][DIM];
    int t = threadIdx.x;
    int rg = t >> 6;
    int lane = t & 63;
    int c0 = lane * 4;
    size_t row0 = (size_t)blockIdx.x * 16;
#pragma unroll 4
    for (int i = 0; i < 16; i++) a[i][t] = X[(row0 + i) * DIM + t];
    __syncthreads();
    float acc[4][4] = {};
    for (int kk = 0; kk < DIM; kk += 4) {
        float af[4][4];
#pragma unroll
        for (int i = 0; i < 4; i++) {
            float4 v = *(const float4*)&a[rg * 4 + i][kk];
            af[i][0] = v.x; af[i][1] = v.y; af[i][2] = v.z; af[i][3] = v.w;
        }
        float wf[4][4];
#pragma unroll
        for (int j2 = 0; j2 < 4; j2++) {
            float4 v = *(const float4*)&W[(size_t)(kk + j2) * DIM + c0];
            wf[j2][0] = v.x; wf[j2][1] = v.y; wf[j2][2] = v.z; wf[j2][3] = v.w;
        }
#pragma unroll
        for (int i = 0; i < 4; i++)
#pragma unroll
            for (int j2 = 0; j2 < 4; j2++)
#pragma unroll
                for (int j = 0; j < 4; j++)
                    acc[i][j] = fmaf(af[i][j2], wf[j2][j], acc[i][j]);
    }
#pragma unroll
    for (int i = 0; i < 4; i++) {
        ushort4 p;
        p.x = f2bf(acc[i][0]); p.y = f2bf(acc[i][1]);
        p.z = f2bf(acc[i][2]); p.w = f2bf(acc[i][3]);
        *(ushort4*)&out[(row0 + rg * 4 + i) * DIM + c0] = p;
    }
}

__global__ void scatter_edges(const int* __restrict__ src, const int* __restrict__ dst,
                              int* __restrict__ count, unsigned short* __restrict__ bucket) {
    int e = blockIdx.x * 256 + threadIdx.x;
    if (e >= NE) return;
    int w = dst[e];
    int pos = atomicAdd(&count[w], 1);
    if (pos < CAP) bucket[(size_t)w * CAP + pos] = (unsigned short)src[e];
}

// w1t[n][k]=bf16(w1[k][n]) (512x256), w2t[n][k]=bf16(w2[k][n]) (256x512)
__global__ void prep_weights(const float* __restrict__ w1, const float* __restrict__ w2,
                             unsigned short* __restrict__ w1t, unsigned short* __restrict__ w2t) {
    int b = blockIdx.x, t = threadIdx.x;
    if (b < DFF) {
        w1t[(size_t)b * 256 + t] = f2bf(w1[(size_t)t * DFF + b]);
    } else {
        int n = b - DFF;
        w2t[(size_t)n * DFF + t]       = f2bf(w2[(size_t)t * 256 + n]);
        w2t[(size_t)n * DFF + t + 256] = f2bf(w2[(size_t)(t + 256) * 256 + n]);
    }
}

// ---------------- GAT: 2 nodes per wave, h -> bf16 ----------------
// Lanes split in halves of 32; each half owns one node. Softmax alphas staged
// through LDS (covers deg<=64: slots hl and hl+32). Output h bf16 (residual
// + elu) written coalesced (32 lanes x 16B = full row).
__global__ __launch_bounds__(256) void gat_h(
    const int* __restrict__ count, const unsigned short* __restrict__ bucket,
    const float* __restrict__ el, const float* __restrict__ Cdst,
    const unsigned short* __restrict__ feat16, const float* __restrict__ word,
    const float* __restrict__ gat_bias, unsigned short* __restrict__ hbf)
{
    __shared__ unsigned short sbuf[8][64];
    __shared__ float abuf[8][4][64];
    int tid = threadIdx.x;
    int lane = tid & 63, wv = tid >> 6;
    int hl = lane & 31, half = lane >> 5;
    int nl = wv * 2 + half;                 // node-local 0..7
    int node = blockIdx.x * 8 + nl;
    int deg = count[node]; if (deg > CAP) deg = CAP;

    // word row, cols hl*8 .. hl*8+7
    const float4* wr = (const float4*)(word + (size_t)node * DIM);
    float4 w0 = wr[hl * 2], w1v = wr[hl * 2 + 1];
    float wcol[8] = {w0.x, w0.y, w0.z, w0.w, w1v.x, w1v.y, w1v.z, w1v.w};

    // er inline: p[h] = sum_k word[k] * Cdst[k][h]
    const float4* Cv = (const float4*)Cdst;
    float p0 = 0.f, p1 = 0.f, p2 = 0.f, p3 = 0.f;
#pragma unroll
    for (int j = 0; j < 8; j++) {
        float4 c = Cv[hl * 8 + j];
        float wj = wcol[j];
        p0 = fmaf(wj, c.x, p0); p1 = fmaf(wj, c.y, p1);
        p2 = fmaf(wj, c.z, p2); p3 = fmaf(wj, c.w, p3);
    }
#pragma unroll
    for (int m = 1; m < 32; m <<= 1) {
        p0 += __shfl_xor(p0, m, 64); p1 += __shfl_xor(p1, m, 64);
        p2 += __shfl_xor(p2, m, 64); p3 += __shfl_xor(p3, m, 64);
    }

    // edge scores for slots hl and hl+32
    int sa = 0, sb = 0;
    float ea0 = -3.4e38f, ea1 = -3.4e38f, ea2 = -3.4e38f, ea3 = -3.4e38f;
    float eb0 = -3.4e38f, eb1 = -3.4e38f, eb2 = -3.4e38f, eb3 = -3.4e38f;
    if (hl < deg) {
        sa = bucket[(size_t)node * CAP + hl];
        float4 e = ((const float4*)el)[sa];
        float v;
        v = e.x + p0; ea0 = v > 0.f ? v : NEG_SLOPE * v;
        v = e.y + p1; ea1 = v > 0.f ? v : NEG_SLOPE * v;
        v = e.z + p2; ea2 = v > 0.f ? v : NEG_SLOPE * v;
        v = e.w + p3; ea3 = v > 0.f ? v : NEG_SLOPE * v;
    }
    if (hl + 32 < deg) {
        sb = bucket[(size_t)node * CAP + hl + 32];
        float4 e = ((const float4*)el)[sb];
        float v;
        v = e.x + p0; eb0 = v > 0.f ? v : NEG_SLOPE * v;
        v = e.y + p1; eb1 = v > 0.f ? v : NEG_SLOPE * v;
        v = e.z + p2; eb2 = v > 0.f ? v : NEG_SLOPE * v;
        v = e.w + p3; eb3 = v > 0.f ? v : NEG_SLOPE * v;
    }
    float m0 = fmaxf(ea0, eb0), m1 = fmaxf(ea1, eb1);
    float m2 = fmaxf(ea2, eb2), m3 = fmaxf(ea3, eb3);
#pragma unroll
    for (int m = 1; m < 32; m <<= 1) {
        m0 = fmaxf(m0, __shfl_xor(m0, m, 64)); m1 = fmaxf(m1, __shfl_xor(m1, m, 64));
        m2 = fmaxf(m2, __shfl_xor(m2, m, 64)); m3 = fmaxf(m3, __shfl_xor(m3, m, 64));
    }
    float xa0 = hl < deg ? expf(ea0 - m0) : 0.f;
    float xa1 = hl < deg ? expf(ea1 - m1) : 0.f;
    float xa2 = hl < deg ? expf(ea2 - m2) : 0.f;
    float xa3 = hl < deg ? expf(ea3 - m3) : 0.f;
    float xb0 = hl + 32 < deg ? expf(eb0 - m0) : 0.f;
    float xb1 = hl + 32 < deg ? expf(eb1 - m1) : 0.f;
    float xb2 = hl + 32 < deg ? expf(eb2 - m2) : 0.f;
    float xb3 = hl + 32 < deg ? expf(eb3 - m3) : 0.f;
    float d0 = xa0 + xb0, d1 = xa1 + xb1, d2 = xa2 + xb2, d3 = xa3 + xb3;
#pragma unroll
    for (int m = 1; m < 32; m <<= 1) {
        d0 += __shfl_xor(d0, m, 64); d1 += __shfl_xor(d1, m, 64);
        d2 += __shfl_xor(d2, m, 64); d3 += __shfl_xor(d3, m, 64);
    }
    float i0 = 1.f / d0, i1 = 1.f / d1, i2 = 1.f / d2, i3 = 1.f / d3;
    sbuf[nl][hl] = (unsigned short)sa;
    sbuf[nl][hl + 32] = (unsigned short)sb;
    abuf[nl][0][hl] = xa0 * i0; abuf[nl][0][hl + 32] = xb0 * i0;
    abuf[nl][1][hl] = xa1 * i1; abuf[nl][1][hl + 32] = xb1 * i1;
    abuf[nl][2][hl] = xa2 * i2; abuf[nl][2][hl + 32] = xb2 * i2;
    abuf[nl][3][hl] = xa3 * i3; abuf[nl][3][hl + 32] = xb3 * i3;
    __syncthreads();

    // gather: lane covers 8 cols, head hh = hl>>3
    int hh = hl >> 3;
    float acc[8] = {};
    for (int i = 0; i < deg; i++) {
        int si = sbuf[nl][i];
        float aa = abuf[nl][hh][i];
        ushortx8 f = *(const ushortx8*)&feat16[(size_t)si * DIM + hl * 8];
#pragma unroll
        for (int j = 0; j < 8; j++) acc[j] = fmaf(aa, bf2f(f[j]), acc[j]);
    }
    float4 g0 = ((const float4*)gat_bias)[hl * 2], g1 = ((const float4*)gat_bias)[hl * 2 + 1];
    float gb[8] = {g0.x, g0.y, g0.z, g0.w, g1.x, g1.y, g1.z, g1.w};
    ushortx8 o;
#pragma unroll
    for (int j = 0; j < 8; j++) {
        float r = acc[j] + gb[j];
        r = r > 0.f ? r : (expf(r) - 1.f);
        o[j] = f2bf(wcol[j] + r);
    }
    *(ushortx8*)&hbf[(size_t)node * DIM + hl * 8] = o;
}

// ---------------- FFN GEMMs: 128x128 tile, mfma 32x32x16, bf16 ----------------
// LDS granule = 16B (8 bf16); slot s of row r holds global granule s^(r&7).
// Waves 2x2, each 64x64 = 2x2 tiles of 32x32. A layout m=lane&31,k=8*half+j;
// C layout col=lane&31, row=(reg&3)+8*(reg>>2)+4*half.

__global__ __launch_bounds__(256) void gemm1_mfma(const unsigned short* __restrict__ hbf,
                                                  const unsigned short* __restrict__ w1t,
                                                  const float* __restrict__ b1,
                                                  unsigned short* __restrict__ hid,
                                                  int slab0, int valid) {
    __shared__ unsigned short As[128 * 64];
    __shared__ unsigned short Bs[128 * 64];
    int tid = threadIdx.x;
    int lane = tid & 63, wv = tid >> 6;
    int wm = wv >> 1, wn = wv & 1;
    int l31 = lane & 31, half = lane >> 5;
    int mrow0 = blockIdx.x * 128;
    int n0 = blockIdx.y * 128;
    floatx16 acc[2][2];
#pragma unroll
    for (int i = 0; i < 2; i++)
#pragma unroll
        for (int j = 0; j < 2; j++) acc[i][j] = (floatx16)(0.f);

    for (int kc = 0; kc < 4; kc++) {
        if (kc) __syncthreads();
#pragma unroll
        for (int it = 0; it < 4; it++) {
            int rbase = wv * 32 + it * 8;
            int r = rbase + (lane >> 3);
            int rl = mrow0 + r; rl = rl < valid ? rl : valid - 1;
            int glf = (lane & 7) ^ (r & 7);
            gload_lds16(hbf + (size_t)(slab0 + rl) * 256 + kc * 64 + glf * 8, &As[rbase * 64]);
        }
#pragma unroll
        for (int it = 0; it < 4; it++) {
            int rbase = wv * 32 + it * 8;
            int r = rbase + (lane >> 3);
            int glf = (lane & 7) ^ (r & 7);
            gload_lds16(w1t + (size_t)(n0 + r) * 256 + kc * 64 + glf * 8, &Bs[rbase * 64]);
        }
        __syncthreads();
#pragma unroll
        for (int ks = 0; ks < 4; ks++) {
            int g = ks * 2 + half;
            bf16x8 a[2], b[2];
#pragma unroll
            for (int mt = 0; mt < 2; mt++) {
                int r = wm * 64 + mt * 32 + l31;
                a[mt] = *(const bf16x8*)&As[r * 64 + ((g ^ r) & 7) * 8];
            }
#pragma unroll
            for (int nt = 0; nt < 2; nt++) {
                int r = wn * 64 + nt * 32 + l31;
                b[nt] = *(const bf16x8*)&Bs[r * 64 + ((g ^ r) & 7) * 8];
            }
#pragma unroll
            for (int mt = 0; mt < 2; mt++)
#pragma unroll
                for (int nt = 0; nt < 2; nt++)
                    acc[mt][nt] = __builtin_amdgcn_mfma_f32_32x32x16_bf16(a[mt], b[nt], acc[mt][nt], 0, 0, 0);
        }
    }
    // epilogue: bias+relu, bf16 stores (32 lanes x 2B = 64B lines)
#pragma unroll
    for (int nt = 0; nt < 2; nt++) {
        int c = n0 + wn * 64 + nt * 32 + l31;
        float bias = b1[c];
#pragma unroll
        for (int mt = 0; mt < 2; mt++) {
#pragma unroll
            for (int reg = 0; reg < 16; reg++) {
                int rloc = mrow0 + wm * 64 + mt * 32 + (reg & 3) + 8 * (reg >> 2) + 4 * half;
                if (rloc < valid) {
                    float v = acc[mt][nt][reg] + bias;
                    v = v > 0.f ? v : 0.f;
                    hid[(size_t)rloc * DFF + c] = f2bf(v);
                }
            }
        }
    }
}

__global__ __launch_bounds__(256) void gemm2_mfma(const unsigned short* __restrict__ hid,
                                                  const unsigned short* __restrict__ w2t,
                                                  const float* __restrict__ b2,
                                                  float* __restrict__ out,
                                                  int slab0, int valid) {
    __shared__ unsigned short As[128 * 64];
    __shared__ unsigned short Bs[128 * 64];
    int tid = threadIdx.x;
    int lane = tid & 63, wv = tid >> 6;
    int wm = wv >> 1, wn = wv & 1;
    int l31 = lane & 31, half = lane >> 5;
    int mrow0 = blockIdx.x * 128;
    int n0 = blockIdx.y * 128;
    floatx16 acc[2][2];
#pragma unroll
    for (int i = 0; i < 2; i++)
#pragma unroll
        for (int j = 0; j < 2; j++) acc[i][j] = (floatx16)(0.f);

    for (int kc = 0; kc < 8; kc++) {
        if (kc) __syncthreads();
#pragma unroll
        for (int it = 0; it < 4; it++) {
            int rbase = wv * 32 + it * 8;
            int r = rbase + (lane >> 3);
            int rl = mrow0 + r; rl = rl < valid ? rl : valid - 1;
            int glf = (lane & 7) ^ (r & 7);
            gload_lds16(hid + (size_t)rl * DFF + kc * 64 + glf * 8, &As[rbase * 64]);
        }
#pragma unroll
        for (int it = 0; it < 4; it++) {
            int rbase = wv * 32 + it * 8;
            int r = rbase + (lane >> 3);
            int glf = (lane & 7) ^ (r & 7);
            gload_lds16(w2t + (size_t)(n0 + r) * DFF + kc * 64 + glf * 8, &Bs[rbase * 64]);
        }
        __syncthreads();
#pragma unroll
        for (int ks = 0; ks < 4; ks++) {
            int g = ks * 2 + half;
            bf16x8 a[2], b[2];
#pragma unroll
            for (int mt = 0; mt < 2; mt++) {
                int r = wm * 64 + mt * 32 + l31;
                a[mt] = *(const bf16x8*)&As[r * 64 + ((g ^ r) & 7) * 8];
            }
#pragma unroll
            for (int nt = 0; nt < 2; nt++) {
                int r = wn * 64 + nt * 32 + l31;
                b[nt] = *(const bf16x8*)&Bs[r * 64 + ((g ^ r) & 7) * 8];
            }
#pragma unroll
            for (int mt = 0; mt < 2; mt++)
#pragma unroll
                for (int nt = 0; nt < 2; nt++)
                    acc[mt][nt] = __builtin_amdgcn_mfma_f32_32x32x16_bf16(a[mt], b[nt], acc[mt][nt], 0, 0, 0);
        }
    }
#pragma unroll
    for (int nt = 0; nt < 2; nt++) {
        int c = n0 + wn * 64 + nt * 32 + l31;
        float bias = b2[c];
#pragma unroll
        for (int mt = 0; mt < 2; mt++) {
#pragma unroll
            for (int reg = 0; reg < 16; reg++) {
                int rloc = mrow0 + wm * 64 + mt * 32 + (reg & 3) + 8 * (reg >> 2) + 4 * half;
                if (rloc < valid)
                    out[(size_t)(slab0 + rloc) * DIM + c] = acc[mt][nt][reg] + bias;
            }
        }
    }
}

// ---------------- launch ----------------
extern "C" void kernel_launch(void* const* d_in, const int* in_sizes, int n_in,
                              void* d_out, int out_size, void* d_ws, size_t ws_size,
                              hipStream_t stream) {
    const float* word   = (const float*)d_in[0];
    const float* sent   = (const float*)d_in[1];
    const int*   src    = (const int*)d_in[2];
    const int*   dst    = (const int*)d_in[3];
    const float* W_src  = (const float*)d_in[4];
    const float* W_dst  = (const float*)d_in[5];
    const float* attn_l = (const float*)d_in[6];
    const float* attn_r = (const float*)d_in[7];
    const float* gbias  = (const float*)d_in[8];
    const float* w1     = (const float*)d_in[9];
    const float* b1     = (const float*)d_in[10];
    const float* w2     = (const float*)d_in[11];
    const float* b2     = (const float*)d_in[12];
    float* out = (float*)d_out;
    // h bf16 lives in the upper half of d_out; gemm2's fp32 writes to earlier
    // rows never reach unread h rows (1024*r < 51.2e6 + 512*r' for r' >= r).
    unsigned short* hbf = (unsigned short*)d_out + (size_t)NW * DIM;

    char* wsb = (char*)d_ws;
    unsigned short* w1t = (unsigned short*)wsb;                 // 512*256
    unsigned short* w2t = w1t + (size_t)DFF * 256;              // 256*512
    float* el    = (float*)(w2t + (size_t)256 * DFF);           // NS*4
    float* C_src = el + (size_t)NS * NH;
    float* C_dst = C_src + DIM * NH;
    unsigned short* feat16 = (unsigned short*)(C_dst + DIM * NH);  // NS*256
    int* count = (int*)(feat16 + (size_t)NS * DIM);             // NW
    unsigned short* bucket = (unsigned short*)(count + NW);     // NW*CAP
    unsigned short* hid = bucket + (size_t)NW * CAP;            // slab of rows x 512
    size_t Rbytes = ws_size - (size_t)((char*)hid - wsb);
    size_t slab_rows = Rbytes / ((size_t)DFF * 2);
    if (slab_rows > NW) slab_rows = NW;
    slab_rows &= ~(size_t)127;

    hipLaunchKernelGGL(zero_count, dim3((NW + 255) / 256), dim3(256), 0, stream, count);
    hipLaunchKernelGGL(compute_C, dim3(2), dim3(256), 0, stream,
                       W_src, attn_l, W_dst, attn_r, C_src, C_dst);
    hipLaunchKernelGGL(prep_weights, dim3(DFF + 256), dim3(256), 0, stream, w1, w2, w1t, w2t);
    hipLaunchKernelGGL(rowdot, dim3(NS / 4), dim3(256), 0, stream, sent, C_src, el, NS);
    hipLaunchKernelGGL(feat_gemm, dim3(NS / 16), dim3(256), 0, stream, sent, W_src, feat16);
    hipLaunchKernelGGL(scatter_edges, dim3(NE / 256), dim3(256), 0, stream, src, dst, count, bucket);
    hipLaunchKernelGGL(gat_h, dim3(NW / 8), dim3(256), 0, stream,
                       count, bucket, el, C_dst, feat16, word, gbias, hbf);

    size_t done = 0;
    while (done < NW) {
        size_t valid = (size_t)NW - done;
        if (valid > slab_rows) valid = slab_rows;
        int gm = (int)((valid + 127) / 128);
        hipLaunchKernelGGL(gemm1_mfma, dim3(gm, 4), dim3(256), 0, stream,
                           hbf, w1t, b1, hid, (int)done, (int)valid);
        hipLaunchKernelGGL(gemm2_mfma, dim3(gm, 2), dim3(256), 0, stream,
                           hid, w2t, b2, out, (int)done, (int)valid);
        done += valid;
    }
}